// Round 2
// baseline (9425.374 us; speedup 1.0000x reference)
//
#include <hip/hip_runtime.h>
#include <hip/hip_bf16.h>

#define HID 128

// ---------------- zero ----------------
__global__ __launch_bounds__(256)
void zero_kernel(float4* __restrict__ p, long n4) {
    long i = (long)blockIdx.x * 256 + threadIdx.x;
    long stride = (long)gridDim.x * 256;
    float4 z = {0.f, 0.f, 0.f, 0.f};
    for (; i < n4; i += stride) p[i] = z;
}

// ---------------- degree / norm ----------------
__global__ __launch_bounds__(256)
void init_deg_kernel(float* __restrict__ deg, int N) {
    int i = blockIdx.x * 256 + threadIdx.x;
    if (i < N) deg[i] = 1.0f;  // self loop
}

__global__ __launch_bounds__(256)
void count_deg_kernel(const int* __restrict__ ei, float* __restrict__ deg, long E) {
    long e = (long)blockIdx.x * 256 + threadIdx.x;
    if (e < E) atomicAdd(&deg[ei[E + e]], 1.0f);
}

__global__ __launch_bounds__(256)
void rsqrt_deg_kernel(float* __restrict__ deg, int N) {
    int i = blockIdx.x * 256 + threadIdx.x;
    if (i < N) deg[i] = rsqrtf(deg[i]);   // deg >= 1 always
}

// ---------------- linear: out[N,128] = h[N,K] @ W[K,128] (+bias, +act) -------
// Block: 512 threads = 16 rows x 32 col-quads. Each thread: 1 row, 4 cols.
template<int K, int ACT, bool BIAS>
__global__ __launch_bounds__(512)
void lin_kernel(const float* __restrict__ X, const float* __restrict__ P,
                const float* __restrict__ Q, const float* __restrict__ W,
                const float* __restrict__ bias, float* __restrict__ out, int N)
{
    __shared__ float hs[16][K];
    int t = threadIdx.x;
    int rr = t >> 5, q = t & 31;
    long r = (long)blockIdx.x * 16 + rr;
    bool valid = r < N;
    if (valid) {
        for (int k = q; k < K; k += 32) {
            float v;
            if (K == 193) {
                v = (k < 128) ? X[r * 128 + k]
                              : (k < 192 ? P[r * 64 + (k - 128)] : Q[r]);
            } else {
                v = X[r * 128 + k];
            }
            hs[rr][k] = v;
        }
    }
    __syncthreads();
    if (!valid) return;
    float4 acc = {0.f, 0.f, 0.f, 0.f};
    #pragma unroll 8
    for (int k = 0; k < K; ++k) {
        float hk = hs[rr][k];
        const float4 w = *reinterpret_cast<const float4*>(W + (long)k * HID + (q << 2));
        acc.x += hk * w.x; acc.y += hk * w.y; acc.z += hk * w.z; acc.w += hk * w.w;
    }
    if (BIAS) {
        const float4 b = *reinterpret_cast<const float4*>(bias + (q << 2));
        acc.x += b.x; acc.y += b.y; acc.z += b.z; acc.w += b.w;
    }
    if (ACT == 1) {  // sigmoid
        acc.x = 1.f / (1.f + expf(-acc.x));
        acc.y = 1.f / (1.f + expf(-acc.y));
        acc.z = 1.f / (1.f + expf(-acc.z));
        acc.w = 1.f / (1.f + expf(-acc.w));
    }
    *reinterpret_cast<float4*>(out + r * HID + (q << 2)) = acc;
}

// ---------------- edge scatter: agg[dst] += m[src] * dis[src]*dis[dst] -------
__global__ __launch_bounds__(256)
void scatter_kernel(const int* __restrict__ ei, const float* __restrict__ dis,
                    const float* __restrict__ m, float* __restrict__ agg, long E)
{
    long i = (long)blockIdx.x * 256 + threadIdx.x;
    if (i >= E * 32) return;
    long e = i >> 5; int q = (int)(i & 31);
    int s = ei[e], d = ei[E + e];
    float nrm = dis[s] * dis[d];
    const float4 v = *reinterpret_cast<const float4*>(m + (long)s * HID + (q << 2));
    float* p = agg + (long)d * HID + (q << 2);
    atomicAdd(p + 0, v.x * nrm);
    atomicAdd(p + 1, v.y * nrm);
    atomicAdd(p + 2, v.z * nrm);
    atomicAdd(p + 3, v.w * nrm);
}

// ---------------- LN + relu + (gate | residual) ------------------------------
// v = agg[r] + dis[r]^2 * m[r] (self loop) + bias
// MODE 0: h[r] = relu(LN(v)) * h[r]   (h holds gate)
// MODE 1: h[r] = h[r] + relu(LN(v))
template<int MODE>
__global__ __launch_bounds__(256)
void ln_post_kernel(const float* __restrict__ agg, const float* __restrict__ m,
                    const float* __restrict__ dis, const float* __restrict__ bias,
                    const float* __restrict__ g, const float* __restrict__ be,
                    float* __restrict__ h, int N)
{
    int wave = threadIdx.x >> 6, lane = threadIdx.x & 63;
    long r = (long)blockIdx.x * 4 + wave;
    if (r >= N) return;
    float d = dis[r]; float d2 = d * d;
    long base = r * HID;
    float v0 = agg[base + lane]      + d2 * m[base + lane]      + bias[lane];
    float v1 = agg[base + 64 + lane] + d2 * m[base + 64 + lane] + bias[64 + lane];
    float s = v0 + v1;
    for (int o = 32; o; o >>= 1) s += __shfl_xor(s, o);
    float mean = s * (1.f / 128.f);
    float a0 = v0 - mean, a1 = v1 - mean;
    float qv = a0 * a0 + a1 * a1;
    for (int o = 32; o; o >>= 1) qv += __shfl_xor(qv, o);
    float rs = rsqrtf(qv * (1.f / 128.f) + 1e-5f);
    float y0 = fmaxf(a0 * rs * g[lane]      + be[lane],      0.f);
    float y1 = fmaxf(a1 * rs * g[64 + lane] + be[64 + lane], 0.f);
    if (MODE == 0) {
        h[base + lane]      = y0 * h[base + lane];
        h[base + 64 + lane] = y1 * h[base + 64 + lane];
    } else {
        h[base + lane]      += y0;
        h[base + 64 + lane] += y1;
    }
}

// ---------------- head: out[r] = relu(h@Wp1+bp1) @ Wp2 + bp2 ----------------
__global__ __launch_bounds__(256)
void head_kernel(const float* __restrict__ h, const float* __restrict__ Wp1,
                 const float* __restrict__ bp1, const float* __restrict__ Wp2,
                 const float* __restrict__ bp2, float* __restrict__ out, int N)
{
    __shared__ float hs[4][HID];
    int wave = threadIdx.x >> 6, lane = threadIdx.x & 63;
    long r = (long)blockIdx.x * 4 + wave;
    if (r < N) {
        hs[wave][lane]      = h[r * HID + lane];
        hs[wave][lane + 64] = h[r * HID + 64 + lane];
    }
    __syncthreads();
    if (r >= N) return;
    float acc = 0.f;
    #pragma unroll 8
    for (int k = 0; k < HID; ++k)
        acc += hs[wave][k] * Wp1[k * 64 + lane];
    float tv = fmaxf(acc + bp1[lane], 0.f);
    float p = tv * Wp2[lane];
    for (int o = 32; o; o >>= 1) p += __shfl_xor(p, o);
    if (lane == 0) out[r] = p + bp2[0];
}

extern "C" void kernel_launch(void* const* d_in, const int* in_sizes, int n_in,
                              void* d_out, int out_size, void* d_ws, size_t ws_size,
                              hipStream_t stream)
{
    const float* x   = (const float*)d_in[0];
    const float* pk  = (const float*)d_in[1];
    const float* pp  = (const float*)d_in[2];
    const int*   ei  = (const int*)d_in[3];     // int32 on device (harness contract)
    const float* W0  = (const float*)d_in[4];
    const float* b0  = (const float*)d_in[5];
    const float* W1  = (const float*)d_in[6];
    const float* b1  = (const float*)d_in[7];
    const float* W2  = (const float*)d_in[8];
    const float* b2  = (const float*)d_in[9];
    const float* g0  = (const float*)d_in[10];
    const float* be0 = (const float*)d_in[11];
    const float* g1  = (const float*)d_in[12];
    const float* be1 = (const float*)d_in[13];
    const float* g2  = (const float*)d_in[14];
    const float* be2 = (const float*)d_in[15];
    const float* Wg  = (const float*)d_in[16];
    const float* bg  = (const float*)d_in[17];
    const float* Wp1 = (const float*)d_in[18];
    const float* bp1 = (const float*)d_in[19];
    const float* Wp2 = (const float*)d_in[20];
    const float* bp2 = (const float*)d_in[21];
    float* out = (float*)d_out;

    int  N = in_sizes[0] / 128;
    long E = in_sizes[3] / 2;

    long Nal = ((long)N + 255) / 256 * 256;   // dis region, 256-float aligned
    float* fws = (float*)d_ws;
    float* dis = fws;
    float* B1  = fws + Nal;                   // m buffer  [N,128]
    float* B2  = B1 + (long)N * HID;          // gate/h    [N,128]
    float* B3  = B2 + (long)N * HID;          // agg       [N,128]

    int nbN   = (N + 255) / 256;
    int nbE   = (int)((E + 255) / 256);
    int nbLin = (N + 15) / 16;
    int nbRow = (N + 3) / 4;
    int nbSc  = (int)((E * 32 + 255) / 256);
    long n4   = (long)N * HID / 4;

    // degree / normalization
    init_deg_kernel<<<nbN, 256, 0, stream>>>(dis, N);
    count_deg_kernel<<<nbE, 256, 0, stream>>>(ei, dis, E);
    rsqrt_deg_kernel<<<nbN, 256, 0, stream>>>(dis, N);

    // gate = sigmoid(h193 @ Wg + bg) -> B2
    lin_kernel<193, 1, true><<<nbLin, 512, 0, stream>>>(x, pk, pp, Wg, bg, B2, N);
    // m0 = h193 @ W0 -> B1
    lin_kernel<193, 0, false><<<nbLin, 512, 0, stream>>>(x, pk, pp, W0, nullptr, B1, N);
    // layer 0 aggregate
    zero_kernel<<<2048, 256, 0, stream>>>((float4*)B3, n4);
    scatter_kernel<<<nbSc, 256, 0, stream>>>(ei, dis, B1, B3, E);
    ln_post_kernel<0><<<nbRow, 256, 0, stream>>>(B3, B1, dis, b0, g0, be0, B2, N);

    // layer 1
    lin_kernel<128, 0, false><<<nbLin, 512, 0, stream>>>(B2, nullptr, nullptr, W1, nullptr, B1, N);
    zero_kernel<<<2048, 256, 0, stream>>>((float4*)B3, n4);
    scatter_kernel<<<nbSc, 256, 0, stream>>>(ei, dis, B1, B3, E);
    ln_post_kernel<1><<<nbRow, 256, 0, stream>>>(B3, B1, dis, b1, g1, be1, B2, N);

    // layer 2
    lin_kernel<128, 0, false><<<nbLin, 512, 0, stream>>>(B2, nullptr, nullptr, W2, nullptr, B1, N);
    zero_kernel<<<2048, 256, 0, stream>>>((float4*)B3, n4);
    scatter_kernel<<<nbSc, 256, 0, stream>>>(ei, dis, B1, B3, E);
    ln_post_kernel<1><<<nbRow, 256, 0, stream>>>(B3, B1, dis, b2, g2, be2, B2, N);

    // head
    head_kernel<<<nbRow, 256, 0, stream>>>(B2, Wp1, bp1, Wp2, bp2, out, N);
}

// Round 3
// 1753.321 us; speedup vs baseline: 5.3757x; 5.3757x over previous
//
#include <hip/hip_runtime.h>
#include <hip/hip_bf16.h>

#define HID 128

// ---------------- zero ----------------
__global__ __launch_bounds__(256)
void zero_int_kernel(int* __restrict__ p, long n) {
    long i = (long)blockIdx.x * 256 + threadIdx.x;
    long stride = (long)gridDim.x * 256;
    for (; i < n; i += stride) p[i] = 0;
}

// ---------------- degree count (int) ----------------
__global__ __launch_bounds__(256)
void count_deg_kernel(const int* __restrict__ ei, int* __restrict__ cnt, long E) {
    long e = (long)blockIdx.x * 256 + threadIdx.x;
    if (e < E) atomicAdd(&cnt[ei[E + e]], 1);
}

__global__ __launch_bounds__(256)
void dis_kernel(const int* __restrict__ cnt, float* __restrict__ dis, int N) {
    int i = blockIdx.x * 256 + threadIdx.x;
    if (i < N) dis[i] = rsqrtf(1.0f + (float)cnt[i]);   // +1 self loop
}

// ---------------- exclusive scan (3-phase) ----------------
__global__ __launch_bounds__(256)
void scan1_kernel(const int* __restrict__ cnt, int* __restrict__ off,
                  int* __restrict__ bsum, int N) {
    __shared__ int sh[256];
    int i = blockIdx.x * 256 + threadIdx.x;
    int v = (i < N) ? cnt[i] : 0;
    sh[threadIdx.x] = v;
    __syncthreads();
    for (int o = 1; o < 256; o <<= 1) {
        int t = 0;
        if (threadIdx.x >= o) t = sh[threadIdx.x - o];
        __syncthreads();
        if (threadIdx.x >= o) sh[threadIdx.x] += t;
        __syncthreads();
    }
    if (i < N) off[i] = sh[threadIdx.x] - v;       // exclusive within block
    if (threadIdx.x == 255) bsum[blockIdx.x] = sh[255];
}

__global__ __launch_bounds__(1024)
void scan2_kernel(int* __restrict__ bsum, int nb) {
    __shared__ int sh[1024];
    int t = threadIdx.x;
    int v = (t < nb) ? bsum[t] : 0;
    sh[t] = v;
    __syncthreads();
    for (int o = 1; o < 1024; o <<= 1) {
        int u = 0;
        if (t >= o) u = sh[t - o];
        __syncthreads();
        if (t >= o) sh[t] += u;
        __syncthreads();
    }
    if (t < nb) bsum[t] = sh[t] - v;               // exclusive
}

__global__ __launch_bounds__(256)
void scan3_kernel(int* __restrict__ off, const int* __restrict__ bsum, int N, int E) {
    int i = blockIdx.x * 256 + threadIdx.x;
    if (i < N) off[i] += bsum[blockIdx.x];
    if (i == 0) off[N] = E;
}

// ---------------- CSR fill ----------------
__global__ __launch_bounds__(256)
void fill_kernel(const int* __restrict__ ei, const int* __restrict__ off,
                 int* __restrict__ cnt, const float* __restrict__ dis,
                 int* __restrict__ csr_src, float* __restrict__ csr_w, long E) {
    long e = (long)blockIdx.x * 256 + threadIdx.x;
    if (e >= E) return;
    int s = ei[e], d = ei[E + e];
    int pos = off[d] + atomicAdd(&cnt[d], 1);
    csr_src[pos] = s;
    csr_w[pos]   = dis[s];
}

// ---------------- linear: out[N,128] = h[N,K] @ W[K,128] (+bias, +act) -------
template<int K, int ACT, bool BIAS>
__global__ __launch_bounds__(512)
void lin_kernel(const float* __restrict__ X, const float* __restrict__ P,
                const float* __restrict__ Q, const float* __restrict__ W,
                const float* __restrict__ bias, float* __restrict__ out, int N)
{
    __shared__ float hs[16][K];
    int t = threadIdx.x;
    int rr = t >> 5, q = t & 31;
    long r = (long)blockIdx.x * 16 + rr;
    bool valid = r < N;
    if (valid) {
        for (int k = q; k < K; k += 32) {
            float v;
            if (K == 193) {
                v = (k < 128) ? X[r * 128 + k]
                              : (k < 192 ? P[r * 64 + (k - 128)] : Q[r]);
            } else {
                v = X[r * 128 + k];
            }
            hs[rr][k] = v;
        }
    }
    __syncthreads();
    if (!valid) return;
    float4 acc = {0.f, 0.f, 0.f, 0.f};
    #pragma unroll 8
    for (int k = 0; k < K; ++k) {
        float hk = hs[rr][k];
        const float4 w = *reinterpret_cast<const float4*>(W + (long)k * HID + (q << 2));
        acc.x += hk * w.x; acc.y += hk * w.y; acc.z += hk * w.z; acc.w += hk * w.w;
    }
    if (BIAS) {
        const float4 b = *reinterpret_cast<const float4*>(bias + (q << 2));
        acc.x += b.x; acc.y += b.y; acc.z += b.z; acc.w += b.w;
    }
    if (ACT == 1) {  // sigmoid
        acc.x = 1.f / (1.f + expf(-acc.x));
        acc.y = 1.f / (1.f + expf(-acc.y));
        acc.z = 1.f / (1.f + expf(-acc.z));
        acc.w = 1.f / (1.f + expf(-acc.w));
    }
    *reinterpret_cast<float4*>(out + r * HID + (q << 2)) = acc;
}

// ------------- fused: CSR gather + self loop + bias + LN + relu + post ------
// v = dis[r] * (sum_e w[e]*m[src[e]] + dis[r]*m[r]) + bias
// MODE 0: h[r] = relu(LN(v)) * h[r]   (h holds gate)
// MODE 1: h[r] = h[r] + relu(LN(v))
template<int MODE>
__global__ __launch_bounds__(256)
void gcn_fused_kernel(const int* __restrict__ off, const int* __restrict__ src,
                      const float* __restrict__ w, const float* __restrict__ dis,
                      const float* __restrict__ m, const float* __restrict__ bias,
                      const float* __restrict__ g, const float* __restrict__ be,
                      float* __restrict__ h, int N)
{
    int wave = threadIdx.x >> 6, lane = threadIdx.x & 63;
    int r = blockIdx.x * 4 + wave;
    if (r >= N) return;
    int beg = off[r], end = off[r + 1];
    float dr = dis[r];
    int c2 = lane << 1;
    float ax = 0.f, ay = 0.f, bx = 0.f, by = 0.f;
    int e = beg;
    for (; e + 2 <= end; e += 2) {
        int s0 = src[e], s1 = src[e + 1];
        float w0 = w[e], w1 = w[e + 1];
        const float2 v0 = *reinterpret_cast<const float2*>(m + (long)s0 * HID + c2);
        const float2 v1 = *reinterpret_cast<const float2*>(m + (long)s1 * HID + c2);
        ax += w0 * v0.x; ay += w0 * v0.y;
        bx += w1 * v1.x; by += w1 * v1.y;
    }
    if (e < end) {
        int s0 = src[e]; float w0 = w[e];
        const float2 v0 = *reinterpret_cast<const float2*>(m + (long)s0 * HID + c2);
        ax += w0 * v0.x; ay += w0 * v0.y;
    }
    const float2 ms = *reinterpret_cast<const float2*>(m + (long)r * HID + c2);
    const float2 bi = *reinterpret_cast<const float2*>(bias + c2);
    float vx = dr * (ax + bx + dr * ms.x) + bi.x;
    float vy = dr * (ay + by + dr * ms.y) + bi.y;
    float s = vx + vy;
    for (int o = 32; o; o >>= 1) s += __shfl_xor(s, o);
    float mean = s * (1.f / 128.f);
    float qx = vx - mean, qy = vy - mean;
    float q = qx * qx + qy * qy;
    for (int o = 32; o; o >>= 1) q += __shfl_xor(q, o);
    float rs = rsqrtf(q * (1.f / 128.f) + 1e-5f);
    const float2 gg = *reinterpret_cast<const float2*>(g + c2);
    const float2 bb = *reinterpret_cast<const float2*>(be + c2);
    float y0 = fmaxf(qx * rs * gg.x + bb.x, 0.f);
    float y1 = fmaxf(qy * rs * gg.y + bb.y, 0.f);
    float2* hp = reinterpret_cast<float2*>(h + (long)r * HID + c2);
    float2 hv = *hp, o2;
    if (MODE == 0) { o2.x = y0 * hv.x; o2.y = y1 * hv.y; }
    else           { o2.x = hv.x + y0; o2.y = hv.y + y1; }
    *hp = o2;
}

// ---------------- head: out[r] = relu(h@Wp1+bp1) @ Wp2 + bp2 ----------------
__global__ __launch_bounds__(256)
void head_kernel(const float* __restrict__ h, const float* __restrict__ Wp1,
                 const float* __restrict__ bp1, const float* __restrict__ Wp2,
                 const float* __restrict__ bp2, float* __restrict__ out, int N)
{
    __shared__ float hs[4][HID];
    int wave = threadIdx.x >> 6, lane = threadIdx.x & 63;
    long r = (long)blockIdx.x * 4 + wave;
    if (r < N) {
        hs[wave][lane]      = h[r * HID + lane];
        hs[wave][lane + 64] = h[r * HID + 64 + lane];
    }
    __syncthreads();
    if (r >= N) return;
    float acc = 0.f;
    #pragma unroll 8
    for (int k = 0; k < HID; ++k)
        acc += hs[wave][k] * Wp1[k * 64 + lane];
    float tv = fmaxf(acc + bp1[lane], 0.f);
    float p = tv * Wp2[lane];
    for (int o = 32; o; o >>= 1) p += __shfl_xor(p, o);
    if (lane == 0) out[r] = p + bp2[0];
}

extern "C" void kernel_launch(void* const* d_in, const int* in_sizes, int n_in,
                              void* d_out, int out_size, void* d_ws, size_t ws_size,
                              hipStream_t stream)
{
    const float* x   = (const float*)d_in[0];
    const float* pk  = (const float*)d_in[1];
    const float* pp  = (const float*)d_in[2];
    const int*   ei  = (const int*)d_in[3];
    const float* W0  = (const float*)d_in[4];
    const float* b0  = (const float*)d_in[5];
    const float* W1  = (const float*)d_in[6];
    const float* b1  = (const float*)d_in[7];
    const float* W2  = (const float*)d_in[8];
    const float* b2  = (const float*)d_in[9];
    const float* g0  = (const float*)d_in[10];
    const float* be0 = (const float*)d_in[11];
    const float* g1  = (const float*)d_in[12];
    const float* be1 = (const float*)d_in[13];
    const float* g2  = (const float*)d_in[14];
    const float* be2 = (const float*)d_in[15];
    const float* Wg  = (const float*)d_in[16];
    const float* bg  = (const float*)d_in[17];
    const float* Wp1 = (const float*)d_in[18];
    const float* bp1 = (const float*)d_in[19];
    const float* Wp2 = (const float*)d_in[20];
    const float* bp2 = (const float*)d_in[21];
    float* out = (float*)d_out;

    int  N = in_sizes[0] / 128;
    long E = in_sizes[3] / 2;

    long Nal = ((long)N + 255) / 256 * 256;
    long Eal = (E + 255) / 256 * 256;
    float* fws     = (float*)d_ws;
    float* dis     = fws;                       // [Nal]
    int*   cnt     = (int*)(dis + Nal);         // [Nal]
    int*   off     = cnt + Nal;                 // [Nal+256]  (needs N+1)
    int*   bsum    = off + Nal + 256;           // [1024]
    int*   csr_src = bsum + 1024;               // [Eal]
    float* csr_w   = (float*)(csr_src + Eal);   // [Eal]
    float* B1      = csr_w + Eal;               // m    [N,128]
    float* B2      = B1 + (long)N * HID;        // h    [N,128]

    int nbN   = (N + 255) / 256;
    int nbE   = (int)((E + 255) / 256);
    int nbLin = (N + 15) / 16;
    int nbRow = (N + 3) / 4;

    // ---- CSR build ----
    zero_int_kernel<<<256, 256, 0, stream>>>(cnt, N);
    count_deg_kernel<<<nbE, 256, 0, stream>>>(ei, cnt, E);
    dis_kernel<<<nbN, 256, 0, stream>>>(cnt, dis, N);
    scan1_kernel<<<nbN, 256, 0, stream>>>(cnt, off, bsum, N);
    scan2_kernel<<<1, 1024, 0, stream>>>(bsum, nbN);
    scan3_kernel<<<nbN, 256, 0, stream>>>(off, bsum, N, (int)E);
    zero_int_kernel<<<256, 256, 0, stream>>>(cnt, N);
    fill_kernel<<<nbE, 256, 0, stream>>>(ei, off, cnt, dis, csr_src, csr_w, E);

    // ---- gate & layer 0 ----
    lin_kernel<193, 1, true><<<nbLin, 512, 0, stream>>>(x, pk, pp, Wg, bg, B2, N);
    lin_kernel<193, 0, false><<<nbLin, 512, 0, stream>>>(x, pk, pp, W0, nullptr, B1, N);
    gcn_fused_kernel<0><<<nbRow, 256, 0, stream>>>(off, csr_src, csr_w, dis, B1, b0, g0, be0, B2, N);

    // ---- layer 1 ----
    lin_kernel<128, 0, false><<<nbLin, 512, 0, stream>>>(B2, nullptr, nullptr, W1, nullptr, B1, N);
    gcn_fused_kernel<1><<<nbRow, 256, 0, stream>>>(off, csr_src, csr_w, dis, B1, b1, g1, be1, B2, N);

    // ---- layer 2 ----
    lin_kernel<128, 0, false><<<nbLin, 512, 0, stream>>>(B2, nullptr, nullptr, W2, nullptr, B1, N);
    gcn_fused_kernel<1><<<nbRow, 256, 0, stream>>>(off, csr_src, csr_w, dis, B1, b2, g2, be2, B2, N);

    // ---- head ----
    head_kernel<<<nbRow, 256, 0, stream>>>(B2, Wp1, bp1, Wp2, bp2, out, N);
}

// Round 4
// 1005.056 us; speedup vs baseline: 9.3780x; 1.7445x over previous
//
#include <hip/hip_runtime.h>
#include <hip/hip_bf16.h>

#define HID 128

// ---------------- zero ----------------
__global__ __launch_bounds__(256)
void zero_int_kernel(int* __restrict__ p, long n) {
    long i = (long)blockIdx.x * 256 + threadIdx.x;
    long stride = (long)gridDim.x * 256;
    for (; i < n; i += stride) p[i] = 0;
}

// ---------------- degree count (int) ----------------
__global__ __launch_bounds__(256)
void count_deg_kernel(const int* __restrict__ ei, int* __restrict__ cnt, long E) {
    long e = (long)blockIdx.x * 256 + threadIdx.x;
    if (e < E) atomicAdd(&cnt[ei[E + e]], 1);
}

__global__ __launch_bounds__(256)
void dis_kernel(const int* __restrict__ cnt, float* __restrict__ dis, int N) {
    int i = blockIdx.x * 256 + threadIdx.x;
    if (i < N) dis[i] = rsqrtf(1.0f + (float)cnt[i]);   // +1 self loop
}

// ---------------- exclusive scan (3-phase) ----------------
__global__ __launch_bounds__(256)
void scan1_kernel(const int* __restrict__ cnt, int* __restrict__ off,
                  int* __restrict__ bsum, int N) {
    __shared__ int sh[256];
    int i = blockIdx.x * 256 + threadIdx.x;
    int v = (i < N) ? cnt[i] : 0;
    sh[threadIdx.x] = v;
    __syncthreads();
    for (int o = 1; o < 256; o <<= 1) {
        int t = 0;
        if (threadIdx.x >= o) t = sh[threadIdx.x - o];
        __syncthreads();
        if (threadIdx.x >= o) sh[threadIdx.x] += t;
        __syncthreads();
    }
    if (i < N) off[i] = sh[threadIdx.x] - v;       // exclusive within block
    if (threadIdx.x == 255) bsum[blockIdx.x] = sh[255];
}

__global__ __launch_bounds__(1024)
void scan2_kernel(int* __restrict__ bsum, int nb) {
    __shared__ int sh[1024];
    int t = threadIdx.x;
    int v = (t < nb) ? bsum[t] : 0;
    sh[t] = v;
    __syncthreads();
    for (int o = 1; o < 1024; o <<= 1) {
        int u = 0;
        if (t >= o) u = sh[t - o];
        __syncthreads();
        if (t >= o) sh[t] += u;
        __syncthreads();
    }
    if (t < nb) bsum[t] = sh[t] - v;               // exclusive
}

__global__ __launch_bounds__(256)
void scan3_kernel(int* __restrict__ off, const int* __restrict__ bsum, int N, int E) {
    int i = blockIdx.x * 256 + threadIdx.x;
    if (i < N) off[i] += bsum[blockIdx.x];
    if (i == 0) off[N] = E;
}

// ---------------- CSR fill ----------------
__global__ __launch_bounds__(256)
void fill_kernel(const int* __restrict__ ei, const int* __restrict__ off,
                 int* __restrict__ cnt, const float* __restrict__ dis,
                 int* __restrict__ csr_src, float* __restrict__ csr_w, long E) {
    long e = (long)blockIdx.x * 256 + threadIdx.x;
    if (e >= E) return;
    int s = ei[e], d = ei[E + e];
    int pos = off[d] + atomicAdd(&cnt[d], 1);
    csr_src[pos] = s;
    csr_w[pos]   = dis[s];
}

// ======== lin2: out[N,128] = h[N,K] @ W[K,128] (+bias, +sigmoid) ========
// 128x128 tile / 256 threads; thread tile = 8 rows x 8 cols (2 float4 col-quads).
// Both operands staged in LDS; K consumed in 64-chunks; K=193 tail special-cased.
template<int K, int ACT, bool BIAS>
__global__ __launch_bounds__(256)
void lin2_kernel(const float* __restrict__ X, const float* __restrict__ P,
                 const float* __restrict__ Q, const float* __restrict__ W,
                 const float* __restrict__ bias, float* __restrict__ out, int N)
{
    constexpr int NCH = K / 64;            // 2 (K=128) or 3 (K=193)
    constexpr bool TAIL = (K == 193);
    __shared__ float hs[64][129];          // [k][row], stride 129: read banks spread
    __shared__ float ws[64][132];          // [k][col], stride 132: 2-way max
    __shared__ float pps[128];
    __shared__ float w192[128];

    int t = threadIdx.x;
    int rg = t >> 4, cg = t & 15;          // 16 row-groups x 16 col-groups
    int row0 = blockIdx.x * 128;

    if (TAIL && t < 128) {
        pps[t]  = Q[min(row0 + t, N - 1)];
        w192[t] = W[192 * HID + t];
    }

    float4 acc0[8], acc1[8];
    #pragma unroll
    for (int i = 0; i < 8; ++i) {
        acc0[i] = make_float4(0.f, 0.f, 0.f, 0.f);
        acc1[i] = make_float4(0.f, 0.f, 0.f, 0.f);
    }

    for (int c = 0; c < NCH; ++c) {
        if (c) __syncthreads();            // protect LDS reuse
        // ---- stage hs_t: h[row][c*64 .. +63] -> hs[k][row]
        {
            int r_l = t >> 1, half = t & 1;
            int r = min(row0 + r_l, N - 1);
            const float* src;
            if (K == 193) src = (c < 2) ? X + (long)r * 128 + c * 64
                                        : P + (long)r * 64;
            else          src = X + (long)r * 128 + c * 64;
            #pragma unroll
            for (int i = 0; i < 8; ++i) {
                float4 v = *reinterpret_cast<const float4*>(src + half * 32 + i * 4);
                int k = half * 32 + i * 4;
                hs[k + 0][r_l] = v.x;
                hs[k + 1][r_l] = v.y;
                hs[k + 2][r_l] = v.z;
                hs[k + 3][r_l] = v.w;
            }
        }
        // ---- stage ws: W[c*64 + k][col]
        {
            int k_l = t >> 2, quad = t & 3;
            const float* src = W + (long)(c * 64 + k_l) * HID + quad * 32;
            #pragma unroll
            for (int i = 0; i < 8; ++i) {
                float4 v = *reinterpret_cast<const float4*>(src + i * 4);
                *reinterpret_cast<float4*>(&ws[k_l][quad * 32 + i * 4]) = v;
            }
        }
        __syncthreads();
        // ---- inner product over this 64-chunk
        #pragma unroll 2
        for (int k = 0; k < 64; ++k) {
            float4 a0 = *reinterpret_cast<const float4*>(&hs[k][rg * 8]);
            float4 a1 = *reinterpret_cast<const float4*>(&hs[k][rg * 8 + 4]);
            float4 w0 = *reinterpret_cast<const float4*>(&ws[k][cg * 4]);
            float4 w1 = *reinterpret_cast<const float4*>(&ws[k][64 + cg * 4]);
            float ar[8] = {a0.x, a0.y, a0.z, a0.w, a1.x, a1.y, a1.z, a1.w};
            #pragma unroll
            for (int i = 0; i < 8; ++i) {
                acc0[i].x += ar[i] * w0.x; acc0[i].y += ar[i] * w0.y;
                acc0[i].z += ar[i] * w0.z; acc0[i].w += ar[i] * w0.w;
                acc1[i].x += ar[i] * w1.x; acc1[i].y += ar[i] * w1.y;
                acc1[i].z += ar[i] * w1.z; acc1[i].w += ar[i] * w1.w;
            }
        }
    }

    if (TAIL) {
        float4 w0 = *reinterpret_cast<const float4*>(&w192[cg * 4]);
        float4 w1 = *reinterpret_cast<const float4*>(&w192[64 + cg * 4]);
        #pragma unroll
        for (int i = 0; i < 8; ++i) {
            float q = pps[rg * 8 + i];
            acc0[i].x += q * w0.x; acc0[i].y += q * w0.y;
            acc0[i].z += q * w0.z; acc0[i].w += q * w0.w;
            acc1[i].x += q * w1.x; acc1[i].y += q * w1.y;
            acc1[i].z += q * w1.z; acc1[i].w += q * w1.w;
        }
    }

    int colA = cg * 4, colB = 64 + cg * 4;
    float4 bA = make_float4(0.f, 0.f, 0.f, 0.f), bB = bA;
    if (BIAS) {
        bA = *reinterpret_cast<const float4*>(bias + colA);
        bB = *reinterpret_cast<const float4*>(bias + colB);
    }
    #pragma unroll
    for (int i = 0; i < 8; ++i) {
        int r = row0 + rg * 8 + i;
        if (r >= N) continue;
        float4 o0 = acc0[i], o1 = acc1[i];
        if (BIAS) {
            o0.x += bA.x; o0.y += bA.y; o0.z += bA.z; o0.w += bA.w;
            o1.x += bB.x; o1.y += bB.y; o1.z += bB.z; o1.w += bB.w;
        }
        if (ACT == 1) {
            o0.x = 1.f / (1.f + expf(-o0.x)); o0.y = 1.f / (1.f + expf(-o0.y));
            o0.z = 1.f / (1.f + expf(-o0.z)); o0.w = 1.f / (1.f + expf(-o0.w));
            o1.x = 1.f / (1.f + expf(-o1.x)); o1.y = 1.f / (1.f + expf(-o1.y));
            o1.z = 1.f / (1.f + expf(-o1.z)); o1.w = 1.f / (1.f + expf(-o1.w));
        }
        *reinterpret_cast<float4*>(out + (long)r * HID + colA) = o0;
        *reinterpret_cast<float4*>(out + (long)r * HID + colB) = o1;
    }
}

// ------------- fused: CSR gather + self loop + bias + LN + relu + post ------
template<int MODE>
__global__ __launch_bounds__(256)
void gcn_fused_kernel(const int* __restrict__ off, const int* __restrict__ src,
                      const float* __restrict__ w, const float* __restrict__ dis,
                      const float* __restrict__ m, const float* __restrict__ bias,
                      const float* __restrict__ g, const float* __restrict__ be,
                      float* __restrict__ h, int N)
{
    int wave = threadIdx.x >> 6, lane = threadIdx.x & 63;
    int r = blockIdx.x * 4 + wave;
    if (r >= N) return;
    int beg = off[r], end = off[r + 1];
    float dr = dis[r];
    int c2 = lane << 1;
    float ax = 0.f, ay = 0.f, bx = 0.f, by = 0.f;
    int e = beg;
    for (; e + 2 <= end; e += 2) {
        int s0 = src[e], s1 = src[e + 1];
        float w0 = w[e], w1 = w[e + 1];
        const float2 v0 = *reinterpret_cast<const float2*>(m + (long)s0 * HID + c2);
        const float2 v1 = *reinterpret_cast<const float2*>(m + (long)s1 * HID + c2);
        ax += w0 * v0.x; ay += w0 * v0.y;
        bx += w1 * v1.x; by += w1 * v1.y;
    }
    if (e < end) {
        int s0 = src[e]; float w0 = w[e];
        const float2 v0 = *reinterpret_cast<const float2*>(m + (long)s0 * HID + c2);
        ax += w0 * v0.x; ay += w0 * v0.y;
    }
    const float2 ms = *reinterpret_cast<const float2*>(m + (long)r * HID + c2);
    const float2 bi = *reinterpret_cast<const float2*>(bias + c2);
    float vx = dr * (ax + bx + dr * ms.x) + bi.x;
    float vy = dr * (ay + by + dr * ms.y) + bi.y;
    float s = vx + vy;
    for (int o = 32; o; o >>= 1) s += __shfl_xor(s, o);
    float mean = s * (1.f / 128.f);
    float qx = vx - mean, qy = vy - mean;
    float q = qx * qx + qy * qy;
    for (int o = 32; o; o >>= 1) q += __shfl_xor(q, o);
    float rs = rsqrtf(q * (1.f / 128.f) + 1e-5f);
    const float2 gg = *reinterpret_cast<const float2*>(g + c2);
    const float2 bb = *reinterpret_cast<const float2*>(be + c2);
    float y0 = fmaxf(qx * rs * gg.x + bb.x, 0.f);
    float y1 = fmaxf(qy * rs * gg.y + bb.y, 0.f);
    float2* hp = reinterpret_cast<float2*>(h + (long)r * HID + c2);
    float2 hv = *hp, o2;
    if (MODE == 0) { o2.x = y0 * hv.x; o2.y = y1 * hv.y; }
    else           { o2.x = hv.x + y0; o2.y = hv.y + y1; }
    *hp = o2;
}

// ======== head2: out[r] = relu(h@Wp1+bp1) @ Wp2 + bp2  (GEMM-structured) ====
__global__ __launch_bounds__(256)
void head2_kernel(const float* __restrict__ h, const float* __restrict__ Wp1,
                  const float* __restrict__ bp1, const float* __restrict__ Wp2,
                  const float* __restrict__ bp2, float* __restrict__ out, int N)
{
    __shared__ float hs[64][129];          // [k][row]
    __shared__ float ws[64][68];           // [k][col 0..63]
    int t = threadIdx.x;
    int rg = t >> 4, cg = t & 15;
    int row0 = blockIdx.x * 128;

    float4 acc[8];
    #pragma unroll
    for (int i = 0; i < 8; ++i) acc[i] = make_float4(0.f, 0.f, 0.f, 0.f);

    for (int c = 0; c < 2; ++c) {
        if (c) __syncthreads();
        {
            int r_l = t >> 1, half = t & 1;
            int r = min(row0 + r_l, N - 1);
            const float* src = h + (long)r * HID + c * 64;
            #pragma unroll
            for (int i = 0; i < 8; ++i) {
                float4 v = *reinterpret_cast<const float4*>(src + half * 32 + i * 4);
                int k = half * 32 + i * 4;
                hs[k + 0][r_l] = v.x;
                hs[k + 1][r_l] = v.y;
                hs[k + 2][r_l] = v.z;
                hs[k + 3][r_l] = v.w;
            }
        }
        {
            int k_l = t >> 2, quad = t & 3;
            const float* src = Wp1 + (long)(c * 64 + k_l) * 64 + quad * 16;
            #pragma unroll
            for (int i = 0; i < 4; ++i) {
                float4 v = *reinterpret_cast<const float4*>(src + i * 4);
                *reinterpret_cast<float4*>(&ws[k_l][quad * 16 + i * 4]) = v;
            }
        }
        __syncthreads();
        #pragma unroll 2
        for (int k = 0; k < 64; ++k) {
            float4 a0 = *reinterpret_cast<const float4*>(&hs[k][rg * 8]);
            float4 a1 = *reinterpret_cast<const float4*>(&hs[k][rg * 8 + 4]);
            float4 w0 = *reinterpret_cast<const float4*>(&ws[k][cg * 4]);
            float ar[8] = {a0.x, a0.y, a0.z, a0.w, a1.x, a1.y, a1.z, a1.w};
            #pragma unroll
            for (int i = 0; i < 8; ++i) {
                acc[i].x += ar[i] * w0.x; acc[i].y += ar[i] * w0.y;
                acc[i].z += ar[i] * w0.z; acc[i].w += ar[i] * w0.w;
            }
        }
    }

    float4 bb = *reinterpret_cast<const float4*>(bp1 + cg * 4);
    float4 w2 = *reinterpret_cast<const float4*>(Wp2 + cg * 4);
    float bp2v = bp2[0];
    #pragma unroll
    for (int i = 0; i < 8; ++i) {
        float4 v = acc[i];
        float s = fmaxf(v.x + bb.x, 0.f) * w2.x + fmaxf(v.y + bb.y, 0.f) * w2.y
                + fmaxf(v.z + bb.z, 0.f) * w2.z + fmaxf(v.w + bb.w, 0.f) * w2.w;
        s += __shfl_xor(s, 1); s += __shfl_xor(s, 2);
        s += __shfl_xor(s, 4); s += __shfl_xor(s, 8);
        int r = row0 + rg * 8 + i;
        if (cg == 0 && r < N) out[r] = s + bp2v;
    }
}

extern "C" void kernel_launch(void* const* d_in, const int* in_sizes, int n_in,
                              void* d_out, int out_size, void* d_ws, size_t ws_size,
                              hipStream_t stream)
{
    const float* x   = (const float*)d_in[0];
    const float* pk  = (const float*)d_in[1];
    const float* pp  = (const float*)d_in[2];
    const int*   ei  = (const int*)d_in[3];
    const float* W0  = (const float*)d_in[4];
    const float* b0  = (const float*)d_in[5];
    const float* W1  = (const float*)d_in[6];
    const float* b1  = (const float*)d_in[7];
    const float* W2  = (const float*)d_in[8];
    const float* b2  = (const float*)d_in[9];
    const float* g0  = (const float*)d_in[10];
    const float* be0 = (const float*)d_in[11];
    const float* g1  = (const float*)d_in[12];
    const float* be1 = (const float*)d_in[13];
    const float* g2  = (const float*)d_in[14];
    const float* be2 = (const float*)d_in[15];
    const float* Wg  = (const float*)d_in[16];
    const float* bg  = (const float*)d_in[17];
    const float* Wp1 = (const float*)d_in[18];
    const float* bp1 = (const float*)d_in[19];
    const float* Wp2 = (const float*)d_in[20];
    const float* bp2 = (const float*)d_in[21];
    float* out = (float*)d_out;

    int  N = in_sizes[0] / 128;
    long E = in_sizes[3] / 2;

    long Nal = ((long)N + 255) / 256 * 256;
    long Eal = (E + 255) / 256 * 256;
    float* fws     = (float*)d_ws;
    float* dis     = fws;                       // [Nal]
    int*   cnt     = (int*)(dis + Nal);         // [Nal]
    int*   off     = cnt + Nal;                 // [Nal+256]  (needs N+1)
    int*   bsum    = off + Nal + 256;           // [1024]
    int*   csr_src = bsum + 1024;               // [Eal]
    float* csr_w   = (float*)(csr_src + Eal);   // [Eal]
    float* B1      = csr_w + Eal;               // m    [N,128]
    float* B2      = B1 + (long)N * HID;        // h    [N,128]

    int nbN    = (N + 255) / 256;
    int nbE    = (int)((E + 255) / 256);
    int nbTile = (N + 127) / 128;
    int nbRow  = (N + 3) / 4;

    // ---- CSR build ----
    zero_int_kernel<<<256, 256, 0, stream>>>(cnt, N);
    count_deg_kernel<<<nbE, 256, 0, stream>>>(ei, cnt, E);
    dis_kernel<<<nbN, 256, 0, stream>>>(cnt, dis, N);
    scan1_kernel<<<nbN, 256, 0, stream>>>(cnt, off, bsum, N);
    scan2_kernel<<<1, 1024, 0, stream>>>(bsum, nbN);
    scan3_kernel<<<nbN, 256, 0, stream>>>(off, bsum, N, (int)E);
    zero_int_kernel<<<256, 256, 0, stream>>>(cnt, N);
    fill_kernel<<<nbE, 256, 0, stream>>>(ei, off, cnt, dis, csr_src, csr_w, E);

    // ---- gate & layer 0 ----
    lin2_kernel<193, 1, true><<<nbTile, 256, 0, stream>>>(x, pk, pp, Wg, bg, B2, N);
    lin2_kernel<193, 0, false><<<nbTile, 256, 0, stream>>>(x, pk, pp, W0, nullptr, B1, N);
    gcn_fused_kernel<0><<<nbRow, 256, 0, stream>>>(off, csr_src, csr_w, dis, B1, b0, g0, be0, B2, N);

    // ---- layer 1 ----
    lin2_kernel<128, 0, false><<<nbTile, 256, 0, stream>>>(B2, nullptr, nullptr, W1, nullptr, B1, N);
    gcn_fused_kernel<1><<<nbRow, 256, 0, stream>>>(off, csr_src, csr_w, dis, B1, b1, g1, be1, B2, N);

    // ---- layer 2 ----
    lin2_kernel<128, 0, false><<<nbTile, 256, 0, stream>>>(B2, nullptr, nullptr, W2, nullptr, B1, N);
    gcn_fused_kernel<1><<<nbRow, 256, 0, stream>>>(off, csr_src, csr_w, dis, B1, b2, g2, be2, B2, N);

    // ---- head ----
    head2_kernel<<<nbTile, 256, 0, stream>>>(B2, Wp1, bp1, Wp2, bp2, out, N);
}

// Round 6
// 807.439 us; speedup vs baseline: 11.6732x; 1.2447x over previous
//
#include <hip/hip_runtime.h>
#include <hip/hip_bf16.h>
#include <hip/hip_fp16.h>

#define HID 128

typedef _Float16 f16x8 __attribute__((ext_vector_type(8)));
typedef float f32x4 __attribute__((ext_vector_type(4)));

// ---------------- zero ----------------
__global__ __launch_bounds__(256)
void zero_int_kernel(int* __restrict__ p, long n) {
    long i = (long)blockIdx.x * 256 + threadIdx.x;
    long stride = (long)gridDim.x * 256;
    for (; i < n; i += stride) p[i] = 0;
}

// ---------------- degree count (int) ----------------
__global__ __launch_bounds__(256)
void count_deg_kernel(const int* __restrict__ ei, int* __restrict__ cnt, long E) {
    long e = (long)blockIdx.x * 256 + threadIdx.x;
    if (e < E) atomicAdd(&cnt[ei[E + e]], 1);
}

__global__ __launch_bounds__(256)
void dis_kernel(const int* __restrict__ cnt, float* __restrict__ dis, int N) {
    int i = blockIdx.x * 256 + threadIdx.x;
    if (i < N) dis[i] = rsqrtf(1.0f + (float)cnt[i]);   // +1 self loop
}

// ---------------- exclusive scan (3-phase) ----------------
__global__ __launch_bounds__(256)
void scan1_kernel(const int* __restrict__ cnt, int* __restrict__ off,
                  int* __restrict__ bsum, int N) {
    __shared__ int sh[256];
    int i = blockIdx.x * 256 + threadIdx.x;
    int v = (i < N) ? cnt[i] : 0;
    sh[threadIdx.x] = v;
    __syncthreads();
    for (int o = 1; o < 256; o <<= 1) {
        int t = 0;
        if (threadIdx.x >= o) t = sh[threadIdx.x - o];
        __syncthreads();
        if (threadIdx.x >= o) sh[threadIdx.x] += t;
        __syncthreads();
    }
    if (i < N) off[i] = sh[threadIdx.x] - v;
    if (threadIdx.x == 255) bsum[blockIdx.x] = sh[255];
}

__global__ __launch_bounds__(1024)
void scan2_kernel(int* __restrict__ bsum, int nb) {
    __shared__ int sh[1024];
    int t = threadIdx.x;
    int v = (t < nb) ? bsum[t] : 0;
    sh[t] = v;
    __syncthreads();
    for (int o = 1; o < 1024; o <<= 1) {
        int u = 0;
        if (t >= o) u = sh[t - o];
        __syncthreads();
        if (t >= o) sh[t] += u;
        __syncthreads();
    }
    if (t < nb) bsum[t] = sh[t] - v;
}

__global__ __launch_bounds__(256)
void scan3_kernel(int* __restrict__ off, const int* __restrict__ bsum, int N, int E) {
    int i = blockIdx.x * 256 + threadIdx.x;
    if (i < N) off[i] += bsum[blockIdx.x];
    if (i == 0) off[N] = E;
}

// ---------------- CSR fill ----------------
__global__ __launch_bounds__(256)
void fill_kernel(const int* __restrict__ ei, const int* __restrict__ off,
                 int* __restrict__ cnt, const float* __restrict__ dis,
                 int* __restrict__ csr_src, float* __restrict__ csr_w, long E) {
    long e = (long)blockIdx.x * 256 + threadIdx.x;
    if (e >= E) return;
    int s = ei[e], d = ei[E + e];
    int pos = off[d] + atomicAdd(&cnt[d], 1);
    csr_src[pos] = s;
    csr_w[pos]   = dis[s];
}

// ---------------- build h193 fp16 [N,224] (zero-padded) ----------------
__global__ __launch_bounds__(256)
void conv193_kernel(const float* __restrict__ x, const float* __restrict__ pk,
                    const float* __restrict__ pp, __half* __restrict__ h16, int N)
{
    long i = (long)blockIdx.x * 256 + threadIdx.x;   // over N*56 col-quads
    if (i >= (long)N * 56) return;
    int r = (int)(i / 56), q = (int)(i - (long)r * 56);
    int c = q * 4;
    float4 v;
    if (c < 128)       v = *reinterpret_cast<const float4*>(x  + (long)r * 128 + c);
    else if (c < 192)  v = *reinterpret_cast<const float4*>(pk + (long)r * 64 + (c - 128));
    else if (c == 192) v = make_float4(pp[r], 0.f, 0.f, 0.f);
    else               v = make_float4(0.f, 0.f, 0.f, 0.f);
    __half h4[4] = {__float2half(v.x), __float2half(v.y), __float2half(v.z), __float2half(v.w)};
    *reinterpret_cast<uint2*>(h16 + (long)r * 224 + c) = *reinterpret_cast<uint2*>(h4);
}

// ---------------- transpose weight: WT[c][k] = W[k][c], fp16, zero-pad k>=K --
__global__ __launch_bounds__(256)
void transpose_w_kernel(const float* __restrict__ W, __half* __restrict__ WT,
                        int K, int KP)
{
    int i = blockIdx.x * 256 + threadIdx.x;
    if (i >= 128 * KP) return;
    int c = i / KP, k = i - c * KP;
    WT[i] = (k < K) ? __float2half(W[(long)k * 128 + c]) : __half(0.f);
}

// ======== MFMA linear: out[N,128] = A16[N,KP] @ W[KP,128] ==================
// 128x128 tile, 4 waves (2x2), wave = 4x4 frags of 16x16x32_f16.
// LDS rows at 80B stride (40 halves) to spread banks.
// OUTMODE 0: write fp16 (message buffer). OUTMODE 1: fp32 sigmoid(acc+bias).
template<int KP, int OUTMODE>
__global__ __launch_bounds__(256)
void mfma_lin_kernel(const __half* __restrict__ A16, const __half* __restrict__ WT,
                     const float* __restrict__ bias, void* __restrict__ outp, int N)
{
    constexpr int NK = KP / 32;
    __shared__ __half Al[128 * 40];
    __shared__ __half Bl[128 * 40];
    int t = threadIdx.x;
    int w = t >> 6, lane = t & 63;
    int wr = (w & 1) * 64, wc = (w >> 1) * 64;
    int row0 = blockIdx.x * 128;
    int lrow = lane & 15, lk = (lane >> 4) * 8;

    f32x4 acc[4][4];
    #pragma unroll
    for (int i = 0; i < 4; ++i)
        #pragma unroll
        for (int j = 0; j < 4; ++j)
            #pragma unroll
            for (int q = 0; q < 4; ++q) acc[i][j][q] = 0.f;

    int sr = t >> 2, sp = t & 3;
    for (int ks = 0; ks < NK; ++ks) {
        if (ks) __syncthreads();
        {
            int rr  = min(row0 + sr, N - 1);
            int rr2 = min(row0 + sr + 64, N - 1);
            *reinterpret_cast<uint4*>(Al + sr * 40 + sp * 8) =
                *reinterpret_cast<const uint4*>(A16 + (long)rr * KP + ks * 32 + sp * 8);
            *reinterpret_cast<uint4*>(Al + (sr + 64) * 40 + sp * 8) =
                *reinterpret_cast<const uint4*>(A16 + (long)rr2 * KP + ks * 32 + sp * 8);
            *reinterpret_cast<uint4*>(Bl + sr * 40 + sp * 8) =
                *reinterpret_cast<const uint4*>(WT + (long)sr * KP + ks * 32 + sp * 8);
            *reinterpret_cast<uint4*>(Bl + (sr + 64) * 40 + sp * 8) =
                *reinterpret_cast<const uint4*>(WT + (long)(sr + 64) * KP + ks * 32 + sp * 8);
        }
        __syncthreads();
        f16x8 af[4], bf[4];
        #pragma unroll
        for (int i = 0; i < 4; ++i) {
            af[i] = *reinterpret_cast<const f16x8*>(Al + (wr + i * 16 + lrow) * 40 + lk);
            bf[i] = *reinterpret_cast<const f16x8*>(Bl + (wc + i * 16 + lrow) * 40 + lk);
        }
        #pragma unroll
        for (int i = 0; i < 4; ++i)
            #pragma unroll
            for (int j = 0; j < 4; ++j)
                acc[i][j] = __builtin_amdgcn_mfma_f32_16x16x32_f16(af[i], bf[j], acc[i][j], 0, 0, 0);
    }

    int orow_b = (lane >> 4) * 4;
    #pragma unroll
    for (int i = 0; i < 4; ++i) {
        #pragma unroll
        for (int j = 0; j < 4; ++j) {
            int col = wc + j * 16 + lrow;
            #pragma unroll
            for (int q = 0; q < 4; ++q) {
                int row = row0 + wr + i * 16 + orow_b + q;
                if (row >= N) continue;
                float v = acc[i][j][q];
                if (OUTMODE == 0) {
                    ((__half*)outp)[(long)row * HID + col] = __float2half(v);
                } else {
                    v += bias[col];
                    ((float*)outp)[(long)row * HID + col] = 1.f / (1.f + expf(-v));
                }
            }
        }
    }
}

// ------------- fused: fp16 CSR gather + self loop + bias + LN + relu + post -
// MODE 0: h[r] = relu(LN(v)) * h[r] (h holds gate); MODE 1: h[r] += relu(LN(v))
// Also writes fp16 copy of h for the next MFMA linear.
template<int MODE>
__global__ __launch_bounds__(256)
void gcn16_kernel(const int* __restrict__ off, const int* __restrict__ src,
                  const float* __restrict__ w, const float* __restrict__ dis,
                  const __half* __restrict__ m16, const float* __restrict__ bias,
                  const float* __restrict__ g, const float* __restrict__ be,
                  float* __restrict__ h, __half* __restrict__ h16o, int N)
{
    int wave = threadIdx.x >> 6, lane = threadIdx.x & 63;
    int r = blockIdx.x * 4 + wave;
    if (r >= N) return;
    int beg = off[r], end = off[r + 1];
    float dr = dis[r];
    int c2 = lane << 1;
    float ax = 0.f, ay = 0.f, bx = 0.f, by = 0.f;
    int e = beg;
    for (; e + 2 <= end; e += 2) {
        int s0 = src[e], s1 = src[e + 1];
        float w0 = w[e], w1 = w[e + 1];
        float2 v0 = __half22float2(*reinterpret_cast<const __half2*>(m16 + (long)s0 * HID + c2));
        float2 v1 = __half22float2(*reinterpret_cast<const __half2*>(m16 + (long)s1 * HID + c2));
        ax += w0 * v0.x; ay += w0 * v0.y;
        bx += w1 * v1.x; by += w1 * v1.y;
    }
    if (e < end) {
        int s0 = src[e]; float w0 = w[e];
        float2 v0 = __half22float2(*reinterpret_cast<const __half2*>(m16 + (long)s0 * HID + c2));
        ax += w0 * v0.x; ay += w0 * v0.y;
    }
    float2 ms = __half22float2(*reinterpret_cast<const __half2*>(m16 + (long)r * HID + c2));
    const float2 bi = *reinterpret_cast<const float2*>(bias + c2);
    float vx = dr * (ax + bx + dr * ms.x) + bi.x;
    float vy = dr * (ay + by + dr * ms.y) + bi.y;
    float s = vx + vy;
    for (int o = 32; o; o >>= 1) s += __shfl_xor(s, o);
    float mean = s * (1.f / 128.f);
    float qx = vx - mean, qy = vy - mean;
    float q = qx * qx + qy * qy;
    for (int o = 32; o; o >>= 1) q += __shfl_xor(q, o);
    float rs = rsqrtf(q * (1.f / 128.f) + 1e-5f);
    const float2 gg = *reinterpret_cast<const float2*>(g + c2);
    const float2 bb = *reinterpret_cast<const float2*>(be + c2);
    float y0 = fmaxf(qx * rs * gg.x + bb.x, 0.f);
    float y1 = fmaxf(qy * rs * gg.y + bb.y, 0.f);
    float2* hp = reinterpret_cast<float2*>(h + (long)r * HID + c2);
    float2 hv = *hp, o2;
    if (MODE == 0) { o2.x = y0 * hv.x; o2.y = y1 * hv.y; }
    else           { o2.x = hv.x + y0; o2.y = hv.y + y1; }
    *hp = o2;
    *reinterpret_cast<__half2*>(h16o + (long)r * HID + c2) = __float22half2_rn(o2);
}

// ======== head2: out[r] = relu(h@Wp1+bp1) @ Wp2 + bp2  (fp32) ==============
__global__ __launch_bounds__(256)
void head2_kernel(const float* __restrict__ h, const float* __restrict__ Wp1,
                  const float* __restrict__ bp1, const float* __restrict__ Wp2,
                  const float* __restrict__ bp2, float* __restrict__ out, int N)
{
    __shared__ float hs[64][129];
    __shared__ float ws[64][68];
    int t = threadIdx.x;
    int rg = t >> 4, cg = t & 15;
    int row0 = blockIdx.x * 128;

    float4 acc[8];
    #pragma unroll
    for (int i = 0; i < 8; ++i) acc[i] = make_float4(0.f, 0.f, 0.f, 0.f);

    for (int c = 0; c < 2; ++c) {
        if (c) __syncthreads();
        {
            int r_l = t >> 1, half = t & 1;
            int r = min(row0 + r_l, N - 1);
            const float* src = h + (long)r * HID + c * 64;
            #pragma unroll
            for (int i = 0; i < 8; ++i) {
                float4 v = *reinterpret_cast<const float4*>(src + half * 32 + i * 4);
                int k = half * 32 + i * 4;
                hs[k + 0][r_l] = v.x;
                hs[k + 1][r_l] = v.y;
                hs[k + 2][r_l] = v.z;
                hs[k + 3][r_l] = v.w;
            }
        }
        {
            int k_l = t >> 2, quad = t & 3;
            const float* src = Wp1 + (long)(c * 64 + k_l) * 64 + quad * 16;
            #pragma unroll
            for (int i = 0; i < 4; ++i) {
                float4 v = *reinterpret_cast<const float4*>(src + i * 4);
                *reinterpret_cast<float4*>(&ws[k_l][quad * 16 + i * 4]) = v;
            }
        }
        __syncthreads();
        #pragma unroll 2
        for (int k = 0; k < 64; ++k) {
            float4 a0 = *reinterpret_cast<const float4*>(&hs[k][rg * 8]);
            float4 a1 = *reinterpret_cast<const float4*>(&hs[k][rg * 8 + 4]);
            float4 w0 = *reinterpret_cast<const float4*>(&ws[k][cg * 4]);
            float ar[8] = {a0.x, a0.y, a0.z, a0.w, a1.x, a1.y, a1.z, a1.w};
            #pragma unroll
            for (int i = 0; i < 8; ++i) {
                acc[i].x += ar[i] * w0.x; acc[i].y += ar[i] * w0.y;
                acc[i].z += ar[i] * w0.z; acc[i].w += ar[i] * w0.w;
            }
        }
    }

    float4 bb = *reinterpret_cast<const float4*>(bp1 + cg * 4);
    float4 w2 = *reinterpret_cast<const float4*>(Wp2 + cg * 4);
    float bp2v = bp2[0];
    #pragma unroll
    for (int i = 0; i < 8; ++i) {
        float4 v = acc[i];
        float s = fmaxf(v.x + bb.x, 0.f) * w2.x + fmaxf(v.y + bb.y, 0.f) * w2.y
                + fmaxf(v.z + bb.z, 0.f) * w2.z + fmaxf(v.w + bb.w, 0.f) * w2.w;
        s += __shfl_xor(s, 1); s += __shfl_xor(s, 2);
        s += __shfl_xor(s, 4); s += __shfl_xor(s, 8);
        int r = row0 + rg * 8 + i;
        if (cg == 0 && r < N) out[r] = s + bp2v;
    }
}

extern "C" void kernel_launch(void* const* d_in, const int* in_sizes, int n_in,
                              void* d_out, int out_size, void* d_ws, size_t ws_size,
                              hipStream_t stream)
{
    const float* x   = (const float*)d_in[0];
    const float* pk  = (const float*)d_in[1];
    const float* pp  = (const float*)d_in[2];
    const int*   ei  = (const int*)d_in[3];
    const float* W0  = (const float*)d_in[4];
    const float* b0  = (const float*)d_in[5];
    const float* W1  = (const float*)d_in[6];
    const float* b1  = (const float*)d_in[7];
    const float* W2  = (const float*)d_in[8];
    const float* b2  = (const float*)d_in[9];
    const float* g0  = (const float*)d_in[10];
    const float* be0 = (const float*)d_in[11];
    const float* g1  = (const float*)d_in[12];
    const float* be1 = (const float*)d_in[13];
    const float* g2  = (const float*)d_in[14];
    const float* be2 = (const float*)d_in[15];
    const float* Wg  = (const float*)d_in[16];
    const float* bg  = (const float*)d_in[17];
    const float* Wp1 = (const float*)d_in[18];
    const float* bp1 = (const float*)d_in[19];
    const float* Wp2 = (const float*)d_in[20];
    const float* bp2 = (const float*)d_in[21];
    float* out = (float*)d_out;

    int  N = in_sizes[0] / 128;
    long E = in_sizes[3] / 2;

    long Nal = ((long)N + 255) / 256 * 256;
    long Eal = (E + 255) / 256 * 256;
    float* fws     = (float*)d_ws;
    float* dis     = fws;                        // [Nal] f32
    int*   cnt     = (int*)(dis + Nal);          // [Nal]
    int*   off     = cnt + Nal;                  // [Nal+256]
    int*   bsum    = off + Nal + 256;            // [1024]
    int*   csr_src = bsum + 1024;                // [Eal]
    float* csr_w   = (float*)(csr_src + Eal);    // [Eal]
    float* B2      = csr_w + Eal;                // h fp32 [N,128]
    __half* M16    = (__half*)(B2 + (long)N * HID);      // m fp16 [N,128]
    __half* H193   = M16 + (long)N * HID;                // fp16 [N,224]
    __half* H128   = H193 + (long)N * 224;               // fp16 [N,128]
    __half* WTg    = H128 + (long)N * HID;               // [128,224]
    __half* WT0    = WTg + 128 * 224;
    __half* WT1    = WT0 + 128 * 224;                    // [128,128]
    __half* WT2    = WT1 + 128 * 128;

    int nbN    = (N + 255) / 256;
    int nbE    = (int)((E + 255) / 256);
    int nbTile = (N + 127) / 128;
    int nbRow  = (N + 3) / 4;
    int nbCv   = (int)(((long)N * 56 + 255) / 256);
    int nbT224 = (128 * 224 + 255) / 256;
    int nbT128 = (128 * 128 + 255) / 256;

    // ---- CSR build ----
    zero_int_kernel<<<256, 256, 0, stream>>>(cnt, N);
    count_deg_kernel<<<nbE, 256, 0, stream>>>(ei, cnt, E);
    dis_kernel<<<nbN, 256, 0, stream>>>(cnt, dis, N);
    scan1_kernel<<<nbN, 256, 0, stream>>>(cnt, off, bsum, N);
    scan2_kernel<<<1, 1024, 0, stream>>>(bsum, nbN);
    scan3_kernel<<<nbN, 256, 0, stream>>>(off, bsum, N, (int)E);
    zero_int_kernel<<<256, 256, 0, stream>>>(cnt, N);
    fill_kernel<<<nbE, 256, 0, stream>>>(ei, off, cnt, dis, csr_src, csr_w, E);

    // ---- fp16 prep ----
    conv193_kernel<<<nbCv, 256, 0, stream>>>(x, pk, pp, H193, N);
    transpose_w_kernel<<<nbT224, 256, 0, stream>>>(Wg, WTg, 193, 224);
    transpose_w_kernel<<<nbT224, 256, 0, stream>>>(W0, WT0, 193, 224);
    transpose_w_kernel<<<nbT128, 256, 0, stream>>>(W1, WT1, 128, 128);
    transpose_w_kernel<<<nbT128, 256, 0, stream>>>(W2, WT2, 128, 128);

    // ---- gate & layer 0 ----
    mfma_lin_kernel<224, 1><<<nbTile, 256, 0, stream>>>(H193, WTg, bg, B2, N);
    mfma_lin_kernel<224, 0><<<nbTile, 256, 0, stream>>>(H193, WT0, nullptr, M16, N);
    gcn16_kernel<0><<<nbRow, 256, 0, stream>>>(off, csr_src, csr_w, dis, M16, b0, g0, be0, B2, H128, N);

    // ---- layer 1 ----
    mfma_lin_kernel<128, 0><<<nbTile, 256, 0, stream>>>(H128, WT1, nullptr, M16, N);
    gcn16_kernel<1><<<nbRow, 256, 0, stream>>>(off, csr_src, csr_w, dis, M16, b1, g1, be1, B2, H128, N);

    // ---- layer 2 ----
    mfma_lin_kernel<128, 0><<<nbTile, 256, 0, stream>>>(H128, WT2, nullptr, M16, N);
    gcn16_kernel<1><<<nbRow, 256, 0, stream>>>(off, csr_src, csr_w, dis, M16, b2, g2, be2, B2, H128, N);

    // ---- head ----
    head2_kernel<<<nbTile, 256, 0, stream>>>(B2, Wp1, bp1, Wp2, bp2, out, N);
}

// Round 11
// 700.309 us; speedup vs baseline: 13.4589x; 1.1530x over previous
//
#include <hip/hip_runtime.h>
#include <hip/hip_bf16.h>
#include <hip/hip_fp16.h>

#define HID 128

typedef _Float16 f16x8 __attribute__((ext_vector_type(8)));
typedef float f32x4 __attribute__((ext_vector_type(4)));

// ---------------- zero ----------------
__global__ __launch_bounds__(256)
void zero_int_kernel(int* __restrict__ p, long n) {
    long i = (long)blockIdx.x * 256 + threadIdx.x;
    long stride = (long)gridDim.x * 256;
    for (; i < n; i += stride) p[i] = 0;
}

// ---------------- degree count (int) ----------------
__global__ __launch_bounds__(256)
void count_deg_kernel(const int* __restrict__ ei, int* __restrict__ cnt, long E) {
    long e = (long)blockIdx.x * 256 + threadIdx.x;
    if (e < E) atomicAdd(&cnt[ei[E + e]], 1);
}

__global__ __launch_bounds__(256)
void dis_kernel(const int* __restrict__ cnt, float* __restrict__ dis, int N) {
    int i = blockIdx.x * 256 + threadIdx.x;
    if (i < N) dis[i] = rsqrtf(1.0f + (float)cnt[i]);   // +1 self loop
}

// ---------------- exclusive scan (3-phase) ----------------
__global__ __launch_bounds__(256)
void scan1_kernel(const int* __restrict__ cnt, int* __restrict__ off,
                  int* __restrict__ bsum, int N) {
    __shared__ int sh[256];
    int i = blockIdx.x * 256 + threadIdx.x;
    int v = (i < N) ? cnt[i] : 0;
    sh[threadIdx.x] = v;
    __syncthreads();
    for (int o = 1; o < 256; o <<= 1) {
        int t = 0;
        if (threadIdx.x >= o) t = sh[threadIdx.x - o];
        __syncthreads();
        if (threadIdx.x >= o) sh[threadIdx.x] += t;
        __syncthreads();
    }
    if (i < N) off[i] = sh[threadIdx.x] - v;
    if (threadIdx.x == 255) bsum[blockIdx.x] = sh[255];
}

__global__ __launch_bounds__(1024)
void scan2_kernel(int* __restrict__ bsum, int nb) {
    __shared__ int sh[1024];
    int t = threadIdx.x;
    int v = (t < nb) ? bsum[t] : 0;
    sh[t] = v;
    __syncthreads();
    for (int o = 1; o < 1024; o <<= 1) {
        int u = 0;
        if (t >= o) u = sh[t - o];
        __syncthreads();
        if (t >= o) sh[t] += u;
        __syncthreads();
    }
    if (t < nb) bsum[t] = sh[t] - v;
}

__global__ __launch_bounds__(256)
void scan3_kernel(int* __restrict__ off, const int* __restrict__ bsum, int N, int E) {
    int i = blockIdx.x * 256 + threadIdx.x;
    if (i < N) off[i] += bsum[blockIdx.x];
    if (i == 0) off[N] = E;
}

// ---------------- CSR fill ----------------
__global__ __launch_bounds__(256)
void fill_kernel(const int* __restrict__ ei, const int* __restrict__ off,
                 int* __restrict__ cnt, const float* __restrict__ dis,
                 int* __restrict__ csr_src, float* __restrict__ csr_w, long E) {
    long e = (long)blockIdx.x * 256 + threadIdx.x;
    if (e >= E) return;
    int s = ei[e], d = ei[E + e];
    int pos = off[d] + atomicAdd(&cnt[d], 1);
    csr_src[pos] = s;
    csr_w[pos]   = dis[s];
}

// ---------------- build h193 fp16 [N,224] (zero-padded) ----------------
__global__ __launch_bounds__(256)
void conv193_kernel(const float* __restrict__ x, const float* __restrict__ pk,
                    const float* __restrict__ pp, __half* __restrict__ h16, int N)
{
    long i = (long)blockIdx.x * 256 + threadIdx.x;   // over N*56 col-quads
    if (i >= (long)N * 56) return;
    int r = (int)(i / 56), q = (int)(i - (long)r * 56);
    int c = q * 4;
    float4 v;
    if (c < 128)       v = *reinterpret_cast<const float4*>(x  + (long)r * 128 + c);
    else if (c < 192)  v = *reinterpret_cast<const float4*>(pk + (long)r * 64 + (c - 128));
    else if (c == 192) v = make_float4(pp[r], 0.f, 0.f, 0.f);
    else               v = make_float4(0.f, 0.f, 0.f, 0.f);
    __half h4[4] = {__float2half(v.x), __float2half(v.y), __float2half(v.z), __float2half(v.w)};
    *reinterpret_cast<uint2*>(h16 + (long)r * 224 + c) = *reinterpret_cast<uint2*>(h4);
}

// ------- transpose weight: WT[c][k] = W[k][c], fp16, zero-pad k>=K ----------
// W is [K, C] row-major; WT is [C, KP].
__global__ __launch_bounds__(256)
void transpose_w_kernel(const float* __restrict__ W, __half* __restrict__ WT,
                        int K, int KP, int C)
{
    int i = blockIdx.x * 256 + threadIdx.x;
    if (i >= C * KP) return;
    int c = i / KP, k = i - c * KP;
    WT[i] = (k < K) ? __float2half(W[(long)k * C + c]) : __half(0.f);
}

// ======== MFMA linear: out[N,128] = A16[N,KP] @ W[KP,128], fp16 out ========
// 128x128 tile, 4 waves (2x2), wave = 4x4 frags of 16x16x32_f16.
// OUTMODE 0: write fp16 raw. OUTMODE 1: write fp16 sigmoid(acc+bias).
template<int KP, int OUTMODE>
__global__ __launch_bounds__(256)
void mfma_lin_kernel(const __half* __restrict__ A16, const __half* __restrict__ WT,
                     const float* __restrict__ bias, __half* __restrict__ outp, int N)
{
    constexpr int NK = KP / 32;
    __shared__ __half Al[128 * 40];
    __shared__ __half Bl[128 * 40];
    int t = threadIdx.x;
    int w = t >> 6, lane = t & 63;
    int wr = (w & 1) * 64, wc = (w >> 1) * 64;
    int row0 = blockIdx.x * 128;
    int lrow = lane & 15, lk = (lane >> 4) * 8;

    f32x4 acc[4][4];
    #pragma unroll
    for (int i = 0; i < 4; ++i)
        #pragma unroll
        for (int j = 0; j < 4; ++j)
            #pragma unroll
            for (int q = 0; q < 4; ++q) acc[i][j][q] = 0.f;

    int sr = t >> 2, sp = t & 3;
    for (int ks = 0; ks < NK; ++ks) {
        if (ks) __syncthreads();
        {
            int rr  = min(row0 + sr, N - 1);
            int rr2 = min(row0 + sr + 64, N - 1);
            *reinterpret_cast<uint4*>(Al + sr * 40 + sp * 8) =
                *reinterpret_cast<const uint4*>(A16 + (long)rr * KP + ks * 32 + sp * 8);
            *reinterpret_cast<uint4*>(Al + (sr + 64) * 40 + sp * 8) =
                *reinterpret_cast<const uint4*>(A16 + (long)rr2 * KP + ks * 32 + sp * 8);
            *reinterpret_cast<uint4*>(Bl + sr * 40 + sp * 8) =
                *reinterpret_cast<const uint4*>(WT + (long)sr * KP + ks * 32 + sp * 8);
            *reinterpret_cast<uint4*>(Bl + (sr + 64) * 40 + sp * 8) =
                *reinterpret_cast<const uint4*>(WT + (long)(sr + 64) * KP + ks * 32 + sp * 8);
        }
        __syncthreads();
        f16x8 af[4], bf[4];
        #pragma unroll
        for (int i = 0; i < 4; ++i) {
            af[i] = *reinterpret_cast<const f16x8*>(Al + (wr + i * 16 + lrow) * 40 + lk);
            bf[i] = *reinterpret_cast<const f16x8*>(Bl + (wc + i * 16 + lrow) * 40 + lk);
        }
        #pragma unroll
        for (int i = 0; i < 4; ++i)
            #pragma unroll
            for (int j = 0; j < 4; ++j)
                acc[i][j] = __builtin_amdgcn_mfma_f32_16x16x32_f16(af[i], bf[j], acc[i][j], 0, 0, 0);
    }

    int orow_b = (lane >> 4) * 4;
    #pragma unroll
    for (int i = 0; i < 4; ++i) {
        #pragma unroll
        for (int j = 0; j < 4; ++j) {
            int col = wc + j * 16 + lrow;
            #pragma unroll
            for (int q = 0; q < 4; ++q) {
                int row = row0 + wr + i * 16 + orow_b + q;
                if (row >= N) continue;
                float v = acc[i][j][q];
                if (OUTMODE == 1) {
                    v += bias[col];
                    v = 1.f / (1.f + expf(-v));
                }
                outp[(long)row * HID + col] = __float2half(v);
            }
        }
    }
}

// ------------- fused: fp16 CSR gather + self loop + bias + LN + relu + post -
// MODE 0: hout[r] = relu(LN(v)) * hin[r]  (hin = gate, fp16)
// MODE 1: hout[r] = hin[r] + relu(LN(v))  (hin == hout = h, fp16)
template<int MODE>
__global__ __launch_bounds__(256)
void gcn16_kernel(const int* __restrict__ off, const int* __restrict__ src,
                  const float* __restrict__ w, const float* __restrict__ dis,
                  const __half* __restrict__ m16, const float* __restrict__ bias,
                  const float* __restrict__ g, const float* __restrict__ be,
                  const __half* __restrict__ hin, __half* __restrict__ hout, int N)
{
    int wave = threadIdx.x >> 6, lane = threadIdx.x & 63;
    int r = blockIdx.x * 4 + wave;
    if (r >= N) return;
    int beg = off[r], end = off[r + 1];
    float dr = dis[r];
    int c2 = lane << 1;
    float ax = 0.f, ay = 0.f, bx = 0.f, by = 0.f;
    float cx = 0.f, cy = 0.f, dx = 0.f, dy = 0.f;
    int e = beg;
    for (; e + 4 <= end; e += 4) {
        int s0 = src[e], s1 = src[e + 1], s2 = src[e + 2], s3 = src[e + 3];
        float w0 = w[e], w1 = w[e + 1], w2 = w[e + 2], w3 = w[e + 3];
        float2 v0 = __half22float2(*reinterpret_cast<const __half2*>(m16 + (long)s0 * HID + c2));
        float2 v1 = __half22float2(*reinterpret_cast<const __half2*>(m16 + (long)s1 * HID + c2));
        float2 v2 = __half22float2(*reinterpret_cast<const __half2*>(m16 + (long)s2 * HID + c2));
        float2 v3 = __half22float2(*reinterpret_cast<const __half2*>(m16 + (long)s3 * HID + c2));
        ax += w0 * v0.x; ay += w0 * v0.y;
        bx += w1 * v1.x; by += w1 * v1.y;
        cx += w2 * v2.x; cy += w2 * v2.y;
        dx += w3 * v3.x; dy += w3 * v3.y;
    }
    for (; e < end; ++e) {
        int s0 = src[e]; float w0 = w[e];
        float2 v0 = __half22float2(*reinterpret_cast<const __half2*>(m16 + (long)s0 * HID + c2));
        ax += w0 * v0.x; ay += w0 * v0.y;
    }
    float2 ms = __half22float2(*reinterpret_cast<const __half2*>(m16 + (long)r * HID + c2));
    const float2 bi = *reinterpret_cast<const float2*>(bias + c2);
    float vx = dr * ((ax + bx) + (cx + dx) + dr * ms.x) + bi.x;
    float vy = dr * ((ay + by) + (cy + dy) + dr * ms.y) + bi.y;
    float s = vx + vy;
    for (int o = 32; o; o >>= 1) s += __shfl_xor(s, o);
    float mean = s * (1.f / 128.f);
    float qx = vx - mean, qy = vy - mean;
    float q = qx * qx + qy * qy;
    for (int o = 32; o; o >>= 1) q += __shfl_xor(q, o);
    float rs = rsqrtf(q * (1.f / 128.f) + 1e-5f);
    const float2 gg = *reinterpret_cast<const float2*>(g + c2);
    const float2 bb = *reinterpret_cast<const float2*>(be + c2);
    float y0 = fmaxf(qx * rs * gg.x + bb.x, 0.f);
    float y1 = fmaxf(qy * rs * gg.y + bb.y, 0.f);
    float2 hv = __half22float2(*reinterpret_cast<const __half2*>(hin + (long)r * HID + c2));
    float2 o2;
    if (MODE == 0) { o2.x = y0 * hv.x; o2.y = y1 * hv.y; }
    else           { o2.x = hv.x + y0; o2.y = hv.y + y1; }
    *reinterpret_cast<__half2*>(hout + (long)r * HID + c2) = __float22half2_rn(o2);
}

// ======== MFMA head: out[r] = relu(h16@Wp1+bp1) @ Wp2 + bp2 ================
// 128 rows x 64 cols per block; 4 waves, each 32 rows; K=128.
__global__ __launch_bounds__(256)
void head3_kernel(const __half* __restrict__ h16, const __half* __restrict__ WTp1,
                  const float* __restrict__ bp1, const float* __restrict__ Wp2,
                  const float* __restrict__ bp2, float* __restrict__ out, int N)
{
    __shared__ __half Al[128 * 40];
    __shared__ __half Bl[64 * 40];
    int t = threadIdx.x;
    int w = t >> 6, lane = t & 63;
    int wr = w * 32;
    int row0 = blockIdx.x * 128;
    int lrow = lane & 15, lk = (lane >> 4) * 8;

    f32x4 acc[2][4];
    #pragma unroll
    for (int i = 0; i < 2; ++i)
        #pragma unroll
        for (int j = 0; j < 4; ++j)
            #pragma unroll
            for (int q = 0; q < 4; ++q) acc[i][j][q] = 0.f;

    int sr = t >> 2, sp = t & 3;
    for (int ks = 0; ks < 4; ++ks) {
        if (ks) __syncthreads();
        {
            int rr  = min(row0 + sr, N - 1);
            int rr2 = min(row0 + sr + 64, N - 1);
            *reinterpret_cast<uint4*>(Al + sr * 40 + sp * 8) =
                *reinterpret_cast<const uint4*>(h16 + (long)rr * HID + ks * 32 + sp * 8);
            *reinterpret_cast<uint4*>(Al + (sr + 64) * 40 + sp * 8) =
                *reinterpret_cast<const uint4*>(h16 + (long)rr2 * HID + ks * 32 + sp * 8);
            if (sr < 64)
                *reinterpret_cast<uint4*>(Bl + sr * 40 + sp * 8) =
                    *reinterpret_cast<const uint4*>(WTp1 + (long)sr * HID + ks * 32 + sp * 8);
        }
        __syncthreads();
        f16x8 af[2], bf[4];
        #pragma unroll
        for (int i = 0; i < 2; ++i)
            af[i] = *reinterpret_cast<const f16x8*>(Al + (wr + i * 16 + lrow) * 40 + lk);
        #pragma unroll
        for (int j = 0; j < 4; ++j)
            bf[j] = *reinterpret_cast<const f16x8*>(Bl + (j * 16 + lrow) * 40 + lk);
        #pragma unroll
        for (int i = 0; i < 2; ++i)
            #pragma unroll
            for (int j = 0; j < 4; ++j)
                acc[i][j] = __builtin_amdgcn_mfma_f32_16x16x32_f16(af[i], bf[j], acc[i][j], 0, 0, 0);
    }

    float bp2v = bp2[0];
    int orow_b = (lane >> 4) * 4;
    #pragma unroll
    for (int i = 0; i < 2; ++i) {
        #pragma unroll
        for (int q = 0; q < 4; ++q) {
            int row = row0 + wr + i * 16 + orow_b + q;
            float p = 0.f;
            #pragma unroll
            for (int j = 0; j < 4; ++j) {
                int col = j * 16 + lrow;
                float tv = fmaxf(acc[i][j][q] + bp1[col], 0.f);
                p += tv * Wp2[col];
            }
            p += __shfl_xor(p, 1); p += __shfl_xor(p, 2);
            p += __shfl_xor(p, 4); p += __shfl_xor(p, 8);
            if (lrow == 0 && row < N) out[row] = p + bp2v;
        }
    }
}

extern "C" void kernel_launch(void* const* d_in, const int* in_sizes, int n_in,
                              void* d_out, int out_size, void* d_ws, size_t ws_size,
                              hipStream_t stream)
{
    const float* x   = (const float*)d_in[0];
    const float* pk  = (const float*)d_in[1];
    const float* pp  = (const float*)d_in[2];
    const int*   ei  = (const int*)d_in[3];
    const float* W0  = (const float*)d_in[4];
    const float* b0  = (const float*)d_in[5];
    const float* W1  = (const float*)d_in[6];
    const float* b1  = (const float*)d_in[7];
    const float* W2  = (const float*)d_in[8];
    const float* b2  = (const float*)d_in[9];
    const float* g0  = (const float*)d_in[10];
    const float* be0 = (const float*)d_in[11];
    const float* g1  = (const float*)d_in[12];
    const float* be1 = (const float*)d_in[13];
    const float* g2  = (const float*)d_in[14];
    const float* be2 = (const float*)d_in[15];
    const float* Wg  = (const float*)d_in[16];
    const float* bg  = (const float*)d_in[17];
    const float* Wp1 = (const float*)d_in[18];
    const float* bp1 = (const float*)d_in[19];
    const float* Wp2 = (const float*)d_in[20];
    const float* bp2 = (const float*)d_in[21];
    float* out = (float*)d_out;

    int  N = in_sizes[0] / 128;
    long E = in_sizes[3] / 2;

    long Nal = ((long)N + 255) / 256 * 256;
    long Eal = (E + 255) / 256 * 256;
    float* fws     = (float*)d_ws;
    float* dis     = fws;                        // [Nal] f32
    int*   cnt     = (int*)(dis + Nal);          // [Nal]
    int*   off     = cnt + Nal;                  // [Nal+256]
    int*   bsum    = off + Nal + 256;            // [1024]
    int*   csr_src = bsum + 1024;                // [Eal]
    float* csr_w   = (float*)(csr_src + Eal);    // [Eal]
    __half* M16    = (__half*)(csr_w + Eal);     // m    fp16 [N,128]
    __half* GATE16 = M16 + (long)N * HID;        // gate fp16 [N,128]
    __half* H16    = GATE16 + (long)N * HID;     // h    fp16 [N,128]
    __half* H193   = H16 + (long)N * HID;        // fp16 [N,224]
    __half* WTg    = H193 + (long)N * 224;       // [128,224]
    __half* WT0    = WTg + 128 * 224;
    __half* WT1    = WT0 + 128 * 224;            // [128,128]
    __half* WT2    = WT1 + 128 * 128;
    __half* WTp1   = WT2 + 128 * 128;            // [64,128]

    int nbN    = (N + 255) / 256;
    int nbE    = (int)((E + 255) / 256);
    int nbTile = (N + 127) / 128;
    int nbRow  = (N + 3) / 4;
    int nbCv   = (int)(((long)N * 56 + 255) / 256);
    int nbT224 = (128 * 224 + 255) / 256;
    int nbT128 = (128 * 128 + 255) / 256;
    int nbTp1  = (64 * 128 + 255) / 256;

    // ---- CSR build ----
    zero_int_kernel<<<256, 256, 0, stream>>>(cnt, N);
    count_deg_kernel<<<nbE, 256, 0, stream>>>(ei, cnt, E);
    dis_kernel<<<nbN, 256, 0, stream>>>(cnt, dis, N);
    scan1_kernel<<<nbN, 256, 0, stream>>>(cnt, off, bsum, N);
    scan2_kernel<<<1, 1024, 0, stream>>>(bsum, nbN);
    scan3_kernel<<<nbN, 256, 0, stream>>>(off, bsum, N, (int)E);
    zero_int_kernel<<<256, 256, 0, stream>>>(cnt, N);
    fill_kernel<<<nbE, 256, 0, stream>>>(ei, off, cnt, dis, csr_src, csr_w, E);

    // ---- fp16 prep ----
    conv193_kernel<<<nbCv, 256, 0, stream>>>(x, pk, pp, H193, N);
    transpose_w_kernel<<<nbT224, 256, 0, stream>>>(Wg, WTg, 193, 224, 128);
    transpose_w_kernel<<<nbT224, 256, 0, stream>>>(W0, WT0, 193, 224, 128);
    transpose_w_kernel<<<nbT128, 256, 0, stream>>>(W1, WT1, 128, 128, 128);
    transpose_w_kernel<<<nbT128, 256, 0, stream>>>(W2, WT2, 128, 128, 128);
    transpose_w_kernel<<<nbTp1, 256, 0, stream>>>(Wp1, WTp1, 128, 128, 64);

    // ---- gate & layer 0 ----
    mfma_lin_kernel<224, 1><<<nbTile, 256, 0, stream>>>(H193, WTg, bg, GATE16, N);
    mfma_lin_kernel<224, 0><<<nbTile, 256, 0, stream>>>(H193, WT0, nullptr, M16, N);
    gcn16_kernel<0><<<nbRow, 256, 0, stream>>>(off, csr_src, csr_w, dis, M16, b0, g0, be0, GATE16, H16, N);

    // ---- layer 1 ----
    mfma_lin_kernel<128, 0><<<nbTile, 256, 0, stream>>>(H16, WT1, nullptr, M16, N);
    gcn16_kernel<1><<<nbRow, 256, 0, stream>>>(off, csr_src, csr_w, dis, M16, b1, g1, be1, H16, H16, N);

    // ---- layer 2 ----
    mfma_lin_kernel<128, 0><<<nbTile, 256, 0, stream>>>(H16, WT2, nullptr, M16, N);
    gcn16_kernel<1><<<nbRow, 256, 0, stream>>>(off, csr_src, csr_w, dis, M16, b2, g2, be2, H16, H16, N);

    // ---- head ----
    head3_kernel<<<nbTile, 256, 0, stream>>>(H16, WTp1, bp1, Wp2, bp2, out, N);
}